// Round 4
// baseline (209.469 us; speedup 1.0000x reference)
//
#include <hip/hip_runtime.h>

// SeesawLoss on MI355X.
// Inputs: d_in[0] = cls_score fp32 (8,16,512,512), d_in[1] = labels i32 (8,512,512),
//         d_in[2] = cum_samples fp32 (16). Output: d_out[0] = scalar loss fp32.
// ws layout (uint32 words):
//   [0 .. 255]    histogram, cacheline-spread: count for class c at word c*16
//   [256 .. 1279] 64 accumulator pairs, pair i at words 256 + i*16 (+0 nll, +1 mask)
//
// R1-R3 lessons: (a) latency/issue-bound, not HBM-bound (L3-hot replays equally slow);
// (b) 1 px/thread = dword loads = 256 B/wave-inst -> issue-limited at ~78 us;
// (c) R1's float4 version serialized because compiler chose 64 total VGPRs.
// R4: float4 x 16 channels (1 KB/wave-inst) + __launch_bounds__(256,4) (VGPR cap 128,
// fits 64 data VGPRs -> all 16 loads in flight) + 4 blocks/CU TLP.

constexpr int   kC      = 16;
constexpr int   kHW     = 512 * 512;               // 2^18
constexpr float kP      = 0.8f;                    // mitigation exponent
constexpr float kLogEps = -4.605170185988091f;     // ln(0.01)
constexpr int   kNAcc   = 64;                      // spread accumulator pairs

__global__ __launch_bounds__(256) void init_ws_k(unsigned int* ws) {
    for (int i = threadIdx.x; i < 256 + kNAcc * 16; i += 256) ws[i] = 0u;
}

// 256 blocks; block b covers contiguous 32 KB of labels (2048 int4). 8 independent
// fully-unrolled int4 loads/thread; register counters; cacheline-spread atomics.
__global__ __launch_bounds__(256) void hist_k(const int4* __restrict__ lab4,
                                              unsigned int* __restrict__ histp) {
    int base = blockIdx.x * 2048 + threadIdx.x;
    int4 v[8];
    #pragma unroll
    for (int j = 0; j < 8; ++j) v[j] = lab4[base + j * 256];   // iter j: contiguous 4 KB
    int cnt[16];
    #pragma unroll
    for (int c = 0; c < 16; ++c) cnt[c] = 0;
    #pragma unroll
    for (int j = 0; j < 8; ++j) {
        #pragma unroll
        for (int c = 0; c < 16; ++c)
            cnt[c] += (v[j].x == c) + (v[j].y == c) + (v[j].z == c) + (v[j].w == c);
    }
    #pragma unroll
    for (int c = 0; c < 16; ++c) {
        int x = cnt[c];
        #pragma unroll
        for (int off = 32; off > 0; off >>= 1) x += __shfl_down(x, off);
        cnt[c] = x;
    }
    __shared__ unsigned int sh[4 * 16];
    int wave = threadIdx.x >> 6, lane = threadIdx.x & 63;
    if (lane == 0) {
        #pragma unroll
        for (int c = 0; c < 16; ++c) sh[wave * 16 + c] = (unsigned)cnt[c];
    }
    __syncthreads();
    int t = threadIdx.x;
    if (t < 16)   // per-class slots 64 B apart -> 256 atomics per line, not 4096
        atomicAdd(&histp[t * 16], sh[t] + sh[16 + t] + sh[32 + t] + sh[48 + t]);
}

// 4 px/thread via float4: 16 channel loads x 16 B/lane, all independent & hoisted.
// 2048 blocks x 256 threads; VGPR cap 128 via launch_bounds keeps all loads in flight.
__global__ __launch_bounds__(256, 4) void seesaw_k(const float* __restrict__ cls,
                                                   const int*   __restrict__ labels,
                                                   const float* __restrict__ cum_in,
                                                   const unsigned int* __restrict__ histp,
                                                   float* __restrict__ ws) {
    __shared__ float s_plog[16];
    __shared__ float s_red[8];
    int t = threadIdx.x;
    if (t < 16) {
        float cc = fmaxf((float)histp[t * 16] + cum_in[t], 1.0f);  // clip(cum, 1, inf)
        s_plog[t] = kP * __logf(cc);
    }
    __syncthreads();

    long long m0 = (long long)(blockIdx.x * 256 + t) * 4;   // first of 4 pixels
    int b  = (int)(m0 >> 18);                               // 4 | 2^18: no batch-crossing
    int hw = (int)(m0 & (kHW - 1));
    const float* pbase = cls + (long long)b * kC * kHW + hw;

    float4 lv[16];
    #pragma unroll
    for (int c = 0; c < 16; ++c)
        lv[c] = *(const float4*)(pbase + (long long)c * kHW);  // 16 x dwordx4 in flight
    const int4 lab4 = *(const int4*)(labels + m0);

    float pl[16];
    #pragma unroll
    for (int c = 0; c < 16; ++c) pl[c] = s_plog[c];            // wave-uniform broadcast

    int labs[4] = {lab4.x, lab4.y, lab4.z, lab4.w};

    float lsum = 0.0f, lcnt = 0.0f;
    #pragma unroll
    for (int p = 0; p < 4; ++p) {
        float l[16];
        #pragma unroll
        for (int c = 0; c < 16; ++c) l[c] = ((const float*)&lv[c])[p];
        int lab = labs[p];

        float m1 = l[0];
        float llab = l[0];                                     // select chain, no dyn index
        #pragma unroll
        for (int c = 1; c < 16; ++c) {
            m1 = fmaxf(m1, l[c]);
            if (c == lab) llab = l[c];
        }
        float s = 0.0f;
        #pragma unroll
        for (int c = 0; c < 16; ++c) s += __expf(l[c] - m1);
        // log(score_mat[c]) = l[c] - K, K = max(llab, m1 + log s + log EPS)
        float K = fmaxf(llab, m1 + __logf(s) + kLogEps);
        float plab = s_plog[lab];                              // LDS gather

        float m2 = -3.0e38f;
        #pragma unroll
        for (int c = 0; c < 16; ++c) {
            // adj = l + log(mit) + log(comp); both clamp to 0 at c==lab -> adj==llab
            float a = l[c] + fminf(0.0f, pl[c] - plab)
                           + fmaxf(0.0f, 2.0f * (l[c] - K));
            l[c] = a;
            m2 = fmaxf(m2, a);
        }
        float s2 = 0.0f;
        #pragma unroll
        for (int c = 0; c < 16; ++c) s2 += __expf(l[c] - m2);
        float nll = m2 + __logf(s2) - llab;                    // -log_softmax(adj)[lab]
        if (lab != 0) { lsum += nll; lcnt += 1.0f; }           // ignore_index = 0
    }

    #pragma unroll
    for (int off = 32; off > 0; off >>= 1) {
        lsum += __shfl_down(lsum, off);
        lcnt += __shfl_down(lcnt, off);
    }
    int wave = t >> 6, lane = t & 63;
    if (lane == 0) { s_red[wave] = lsum; s_red[4 + wave] = lcnt; }
    __syncthreads();
    if (t == 0) {
        float* pair = ws + 256 + (blockIdx.x & (kNAcc - 1)) * 16;   // 64 B-spread pairs
        atomicAdd(&pair[0], s_red[0] + s_red[1] + s_red[2] + s_red[3]);
        atomicAdd(&pair[1], s_red[4] + s_red[5] + s_red[6] + s_red[7]);
    }
}

__global__ void final_k(const float* __restrict__ ws, float* __restrict__ out) {
    int t = threadIdx.x;                           // one wave
    float a = (t < kNAcc) ? ws[256 + t * 16]     : 0.0f;
    float b = (t < kNAcc) ? ws[256 + t * 16 + 1] : 0.0f;
    #pragma unroll
    for (int off = 32; off > 0; off >>= 1) {
        a += __shfl_down(a, off);
        b += __shfl_down(b, off);
    }
    if (t == 0) out[0] = a / b;
}

extern "C" void kernel_launch(void* const* d_in, const int* in_sizes, int n_in,
                              void* d_out, int out_size, void* d_ws, size_t ws_size,
                              hipStream_t stream) {
    const float* cls    = (const float*)d_in[0];
    const int*   labels = (const int*)d_in[1];
    const float* cum_in = (const float*)d_in[2];
    float* out = (float*)d_out;
    unsigned int* ws = (unsigned int*)d_ws;

    int M  = in_sizes[1];        // 2,097,152 pixels
    int n4 = M / 4;

    init_ws_k<<<1, 256, 0, stream>>>(ws);
    hist_k<<<n4 / 2048, 256, 0, stream>>>((const int4*)labels, ws);
    seesaw_k<<<M / 1024, 256, 0, stream>>>(cls, labels, cum_in, ws, (float*)ws);
    final_k<<<1, 64, 0, stream>>>((const float*)ws, out);
}